// Round 9
// baseline (4897.556 us; speedup 1.0000x reference)
//
#include <hip/hip_runtime.h>
#include <hip/hip_bf16.h>
#include <hip/hip_fp16.h>

// ---------------------------------------------------------------------------
// GRU forward, MI355X.
//   B=32, L=2048, D=256, H=256, 3H=768.
//   Phase 0: convert x,W_ih -> bf16 ; W_hh -> f16
//   Phase 1: xg = x @ W_ih^T + b_ih  via MFMA bf16 16x16x32, 128x128 tiles
//   Phase 2: persistent recurrence, 1 WG per batch (32 WGs).
//     ROUND-9 CHANGE: R8's AGPR pin compiled the writes (a64 seen in the
//     error text) but gfx950 VALU dots CANNOT source AGPRs -> add the legal
//     1-op tax: volatile v_accvgpr_read to a temp VGPR, then v_dot2 on it.
//     Volatile prevents LICM hoisting 192 reads out of the loop (which would
//     recreate the 192-live-VGPR pressure the RA refuses). Capacity: 192
//     AGPR + ~45 arch VGPR = 237 < 256/wave budget (512 thr = 2 waves/SIMD)
//     -> no spill motive. Model ~1700 cy/step (read tax = 2x the 768cy dot2
//     floor; next round migrates chunks to arch VGPRs if residency proves).
// ---------------------------------------------------------------------------

typedef __attribute__((ext_vector_type(8))) short s8v;
typedef __attribute__((ext_vector_type(4))) float f4v;

// ---------------- converts ----------------

__device__ __forceinline__ unsigned short f2bf_rne(unsigned u) {
  return (unsigned short)((u + 0x7FFFu + ((u >> 16) & 1u)) >> 16);
}

__global__ void cvt_bf16_k(const float* __restrict__ s, unsigned short* __restrict__ d, int n8) {
  int i = blockIdx.x * blockDim.x + threadIdx.x;
  int st = gridDim.x * blockDim.x;
  const uint4* sp = (const uint4*)s;
  for (; i < n8; i += st) {
    uint4 a = sp[2 * i], b = sp[2 * i + 1];
    union { unsigned short us[8]; uint4 u; } o;
    o.us[0] = f2bf_rne(a.x); o.us[1] = f2bf_rne(a.y);
    o.us[2] = f2bf_rne(a.z); o.us[3] = f2bf_rne(a.w);
    o.us[4] = f2bf_rne(b.x); o.us[5] = f2bf_rne(b.y);
    o.us[6] = f2bf_rne(b.z); o.us[7] = f2bf_rne(b.w);
    ((uint4*)d)[i] = o.u;
  }
}

__global__ void cvt_f16_k(const float* __restrict__ s, __half* __restrict__ d, int n8) {
  int i = blockIdx.x * blockDim.x + threadIdx.x;
  int st = gridDim.x * blockDim.x;
  const float4* sp = (const float4*)s;
  for (; i < n8; i += st) {
    float4 a = sp[2 * i], b = sp[2 * i + 1];
    union { uint4 u; __half2 h[4]; } o;
    o.h[0] = __floats2half2_rn(a.x, a.y);
    o.h[1] = __floats2half2_rn(a.z, a.w);
    o.h[2] = __floats2half2_rn(b.x, b.y);
    o.h[3] = __floats2half2_rn(b.z, b.w);
    ((uint4*)d)[i] = o.u;
  }
}

// ---------------- phase 1: xg GEMM (bf16 MFMA) ----------------
#define BT 48

__global__ __launch_bounds__(256) void gemm_xg(
    const unsigned short* __restrict__ X, const unsigned short* __restrict__ W,
    const float* __restrict__ bias, __half* __restrict__ XG) {
  __shared__ unsigned short As[128 * BT];
  __shared__ unsigned short Bs[128 * BT];
  const int tid = threadIdx.x;
  const int bm = blockIdx.x, bn = blockIdx.y;
  const int w = tid >> 6, l = tid & 63;
  const int wr = (w >> 1) * 64, wc = (w & 1) * 64;

  f4v acc[4][4];
#pragma unroll
  for (int a = 0; a < 4; ++a)
#pragma unroll
    for (int b = 0; b < 4; ++b) {
      acc[a][b][0] = 0.f; acc[a][b][1] = 0.f; acc[a][b][2] = 0.f; acc[a][b][3] = 0.f;
    }

  const long arow0 = (long)bm * 128;
  const int brow0 = bn * 128;

  for (int kb = 0; kb < 256; kb += 32) {
#pragma unroll
    for (int cc = 0; cc < 2; ++cc) {
      int c = tid + cc * 256;
      int row = c >> 2, part = c & 3;
      uint4 av = *(const uint4*)(X + (arow0 + row) * 256 + kb + part * 8);
      *(uint4*)(&As[row * BT + part * 8]) = av;
      uint4 bv = *(const uint4*)(W + (long)(brow0 + row) * 256 + kb + part * 8);
      *(uint4*)(&Bs[row * BT + part * 8]) = bv;
    }
    __syncthreads();

    const int lr = l & 15, kg = (l >> 4) * 8;
    s8v af[4], bf[4];
#pragma unroll
    for (int mi = 0; mi < 4; ++mi) af[mi] = *(const s8v*)(&As[(wr + mi * 16 + lr) * BT + kg]);
#pragma unroll
    for (int ni = 0; ni < 4; ++ni) bf[ni] = *(const s8v*)(&Bs[(wc + ni * 16 + lr) * BT + kg]);
#pragma unroll
    for (int mi = 0; mi < 4; ++mi)
#pragma unroll
      for (int ni = 0; ni < 4; ++ni)
        acc[mi][ni] = __builtin_amdgcn_mfma_f32_16x16x32_bf16(af[mi], bf[ni], acc[mi][ni], 0, 0, 0);
    __syncthreads();
  }

  const int lr = l & 15, rg = (l >> 4) * 4;
#pragma unroll
  for (int mi = 0; mi < 4; ++mi)
#pragma unroll
    for (int ni = 0; ni < 4; ++ni) {
      int gcol = bn * 128 + wc + ni * 16 + lr;
      float bv = bias[gcol];
#pragma unroll
      for (int r = 0; r < 4; ++r) {
        long grow = arow0 + wr + mi * 16 + rg + r;
        XG[grow * 768 + gcol] = __float2half(acc[mi][ni][r] + bv);
      }
    }
}

// ---------------- phase 2: recurrence ----------------

__device__ __forceinline__ float rcp_fast(float x) {
#if __has_builtin(__builtin_amdgcn_rcpf)
  return __builtin_amdgcn_rcpf(x);
#else
  return 1.f / x;
#endif
}

#define FOR16A(M) M(0) M(1) M(2) M(3) M(4) M(5) M(6) M(7) \
                  M(8) M(9) M(10) M(11) M(12) M(13) M(14) M(15)
#define FOR16B(M) M(16) M(17) M(18) M(19) M(20) M(21) M(22) M(23) \
                  M(24) M(25) M(26) M(27) M(28) M(29) M(30) M(31)
#define FOR16C(M) M(16,0) M(17,1) M(18,2) M(19,3) M(20,4) M(21,5) M(22,6) M(23,7) \
                  M(24,8) M(25,9) M(26,10) M(27,11) M(28,12) M(29,13) M(30,14) M(31,15)

// weight dword -> AGPR (class-pinned, non-rematerializable asm def)
#define DECL_W(J) unsigned w##J##_0, w##J##_1, w##J##_2, w##J##_3; \
  { uint4 q = wr4[(J)]; \
    asm volatile("v_accvgpr_write_b32 %0, %1" : "=a"(w##J##_0) : "v"(q.x)); \
    asm volatile("v_accvgpr_write_b32 %0, %1" : "=a"(w##J##_1) : "v"(q.y)); \
    asm volatile("v_accvgpr_write_b32 %0, %1" : "=a"(w##J##_2) : "v"(q.z)); \
    asm volatile("v_accvgpr_write_b32 %0, %1" : "=a"(w##J##_3) : "v"(q.w)); }
#define DECL_U(J) unsigned u##J##_0, u##J##_1, u##J##_2, u##J##_3; \
  { uint4 q = un4[(J)]; \
    asm volatile("v_accvgpr_write_b32 %0, %1" : "=a"(u##J##_0) : "v"(q.x)); \
    asm volatile("v_accvgpr_write_b32 %0, %1" : "=a"(u##J##_1) : "v"(q.y)); \
    asm volatile("v_accvgpr_write_b32 %0, %1" : "=a"(u##J##_2) : "v"(q.z)); \
    asm volatile("v_accvgpr_write_b32 %0, %1" : "=a"(u##J##_3) : "v"(q.w)); }

// AGPR weight -> temp VGPR (volatile: keeps the read in-loop, no LICM)
// then f16x2 dot with f32 accumulate. 2 VALU ops per 2 MACs.
#define DOT(ACC, W, H) { unsigned wt_; \
  asm volatile("v_accvgpr_read_b32 %0, %1" : "=v"(wt_) : "a"(W)); \
  asm("v_dot2_f32_f16 %0, %1, %2, %0" : "+v"(ACC) : "v"(wt_), "v"(H)); }

#define CHF(J) { uint4 hq = hp[(J)]; \
  DOT(a0, w##J##_0, hq.x) DOT(a1, w##J##_1, hq.y) \
  DOT(a2, w##J##_2, hq.z) DOT(a3, w##J##_3, hq.w) }
#define CHN(J, U) { uint4 hq = hp[(J)]; \
  DOT(a0, w##J##_0, hq.x) DOT(a1, w##J##_1, hq.y) \
  DOT(a2, w##J##_2, hq.z) DOT(a3, w##J##_3, hq.w) \
  DOT(b0, u##U##_0, hq.x) DOT(b1, u##U##_1, hq.y) \
  DOT(b2, u##U##_2, hq.z) DOT(b3, u##U##_3, hq.w) }
#define CHN1(J) CHN(J, J)

// 32 blocks x 512 threads (8 waves). grp = tid>>8 (wave-uniform).
//  grp0 (tid 0..255):   update row i (full K)  + new-row(512+i) k in [0,128)
//  grp1 (tid 256..511): reset  row 256+i (full K) + new-row(512+i) k in [128,256)
__global__ __launch_bounds__(512)
__attribute__((amdgpu_waves_per_eu(2, 2)))
void gru_rec(
    const __half* __restrict__ Whh, const __half* __restrict__ XG,
    float* __restrict__ Y) {
  const int b = blockIdx.x;
  const int tid = threadIdx.x;
  const int i = tid & 255;
  const int grp = tid >> 8;

  __shared__ __align__(16) __half hl[256];
  __shared__ float r_l[256];
  __shared__ float p1_l[256];

  const uint4* wr4 = (const uint4*)(Whh + (long)tid * 256);
  const uint4* un4 = (const uint4*)(Whh + (long)(512 + i) * 256 + grp * 128);

  // 192 AGPR dwords per thread: full gate row (128) + new-gate half row (64)
  FOR16A(DECL_W)
  FOR16B(DECL_W)
  FOR16A(DECL_U)

  if (grp == 0) hl[i] = __float2half(0.f);
  float h_old = 0.f;
  __syncthreads();

  const long base = (long)b * 2048 * 768;
  const long ybase = (long)b * 2048 * 256;
  const int colA = grp ? (256 + i) : i;
  const uint4* hp = (const uint4*)hl;

  __half va_c = XG[base + colA];
  __half vb_c = __float2half(0.f);
  if (!grp) vb_c = XG[base + 512 + i];

  for (int t = 0; t < 2048; ++t) {
    const long nx = base + (long)(t + 1 < 2048 ? t + 1 : 2047) * 768;
    __half va_n = XG[nx + colA];
    __half vb_n = vb_c;
    if (!grp) vb_n = XG[nx + 512 + i];

    float a0 = 0.f, a1 = 0.f, a2 = 0.f, a3 = 0.f;
    float b0 = 0.f, b1 = 0.f, b2 = 0.f, b3 = 0.f;
    if (!grp) {
      FOR16A(CHN1)  // chunks 0-15: full-row + new-row (k-half 0)
      FOR16B(CHF)   // chunks 16-31: full-row only
    } else {
      FOR16A(CHF)   // chunks 0-15: full-row only
      FOR16C(CHN)   // chunks 16-31: full-row + new-row (k-half 1, u0..u15)
    }

    const float dF = (a0 + a1) + (a2 + a3);  // h_u (grp0) / h_r (grp1)
    const float dH = (b0 + b1) + (b2 + b3);  // partial h_n
    const float xv = __half2float(va_c);

    if (grp) {
      float r = rcp_fast(1.f + __expf(-(xv + dF)));
      r_l[i] = r;
      p1_l[i] = dH;
    }
    __syncthreads();
    if (!grp) {
      float z = rcp_fast(1.f + __expf(-(xv + dF)));
      float hn = dH + p1_l[i];
      float pre = __half2float(vb_c) + r_l[i] * hn;
      float e = __expf(2.f * pre);
      float n = 1.f - 2.f * rcp_fast(1.f + e);
      float hnew = z * h_old + (1.f - z) * n;
      Y[ybase + (long)t * 256 + i] = hnew;
      hl[i] = __float2half(hnew);
      h_old = hnew;
    }
    __syncthreads();
    va_c = va_n;
    vb_c = vb_n;
  }
}

// ---------------- launch ----------------

extern "C" void kernel_launch(void* const* d_in, const int* in_sizes, int n_in,
                              void* d_out, int out_size, void* d_ws, size_t ws_size,
                              hipStream_t stream) {
  const float* x   = (const float*)d_in[0];  // [32,2048,256]
  const float* Wih = (const float*)d_in[1];  // [768,256]
  const float* bih = (const float*)d_in[2];  // [768]
  const float* Whh = (const float*)d_in[3];  // [768,256]
  float* Y = (float*)d_out;                  // [32,2048,256]

  char* ws = (char*)d_ws;
  unsigned short* x16   = (unsigned short*)ws;
  unsigned short* wih16 = (unsigned short*)(ws + 33554432);
  __half*         whh16 = (__half*)(ws + 33554432 + 393216);
  __half*         xg16  = (__half*)(ws + 33554432 + 2 * 393216);

  cvt_bf16_k<<<2048, 256, 0, stream>>>(x, x16, 16777216 / 8);
  cvt_bf16_k<<<96, 256, 0, stream>>>(Wih, wih16, 196608 / 8);
  cvt_f16_k<<<96, 256, 0, stream>>>(Whh, whh16, 196608 / 8);

  dim3 g(512, 6);
  gemm_xg<<<g, 256, 0, stream>>>(x16, wih16, bih, xg16);

  gru_rec<<<32, 512, 0, stream>>>(whh16, xg16, Y);
}

// Round 11
// 4216.143 us; speedup vs baseline: 1.1616x; 1.1616x over previous
//
#include <hip/hip_runtime.h>
#include <hip/hip_bf16.h>
#include <hip/hip_fp16.h>

// ---------------------------------------------------------------------------
// GRU forward, MI355X.
//   B=32, L=2048, D=256, H=256, 3H=768.
//   Phase 0: convert x,W_ih -> bf16 ; W_hh -> f16
//   Phase 1: xg = x @ W_ih^T + b_ih  via MFMA bf16 16x16x32, 128x128 tiles
//   Phase 2: persistent recurrence, 1 WG per batch (32 WGs).
//     ROUND-11: R10 geometry (the fix) with R1-R6-proven constructs (the
//     crash avoidance). Capacity: weights 384KB/CU = 75% of regfile, so
//     T=256 (1 wave/SIMD, 512-reg budget) is the ONLY feasible config:
//     384 weight regs + ~70 working < 512. Loads are plain C++ uint4
//     (ran R1-R4), residency forced by R6's asm"+v" PIN (ran R6): PIN
//     makes values non-remat asm results, and with budget slack the RA
//     has no spill motive. Thread (rs,kq): K-quarter kq of 12 rows;
//     DPP quad butterfly (pure VALU) reduces; 1 barrier/step.
// ---------------------------------------------------------------------------

typedef _Float16 h2v __attribute__((ext_vector_type(2)));
typedef _Float16 h8  __attribute__((ext_vector_type(8)));
typedef __attribute__((ext_vector_type(8))) short s8v;
typedef __attribute__((ext_vector_type(4))) float f4v;

#define PAIR(v, k) __builtin_shufflevector((v), (v), 2 * (k), 2 * (k) + 1)

// ---------------- converts ----------------

__device__ __forceinline__ unsigned short f2bf_rne(unsigned u) {
  return (unsigned short)((u + 0x7FFFu + ((u >> 16) & 1u)) >> 16);
}

__global__ void cvt_bf16_k(const float* __restrict__ s, unsigned short* __restrict__ d, int n8) {
  int i = blockIdx.x * blockDim.x + threadIdx.x;
  int st = gridDim.x * blockDim.x;
  const uint4* sp = (const uint4*)s;
  for (; i < n8; i += st) {
    uint4 a = sp[2 * i], b = sp[2 * i + 1];
    union { unsigned short us[8]; uint4 u; } o;
    o.us[0] = f2bf_rne(a.x); o.us[1] = f2bf_rne(a.y);
    o.us[2] = f2bf_rne(a.z); o.us[3] = f2bf_rne(a.w);
    o.us[4] = f2bf_rne(b.x); o.us[5] = f2bf_rne(b.y);
    o.us[6] = f2bf_rne(b.z); o.us[7] = f2bf_rne(b.w);
    ((uint4*)d)[i] = o.u;
  }
}

__global__ void cvt_f16_k(const float* __restrict__ s, __half* __restrict__ d, int n8) {
  int i = blockIdx.x * blockDim.x + threadIdx.x;
  int st = gridDim.x * blockDim.x;
  const float4* sp = (const float4*)s;
  for (; i < n8; i += st) {
    float4 a = sp[2 * i], b = sp[2 * i + 1];
    union { uint4 u; __half2 h[4]; } o;
    o.h[0] = __floats2half2_rn(a.x, a.y);
    o.h[1] = __floats2half2_rn(a.z, a.w);
    o.h[2] = __floats2half2_rn(b.x, b.y);
    o.h[3] = __floats2half2_rn(b.z, b.w);
    ((uint4*)d)[i] = o.u;
  }
}

// ---------------- phase 1: xg GEMM (bf16 MFMA) ----------------
#define BT 48

__global__ __launch_bounds__(256) void gemm_xg(
    const unsigned short* __restrict__ X, const unsigned short* __restrict__ W,
    const float* __restrict__ bias, __half* __restrict__ XG) {
  __shared__ unsigned short As[128 * BT];
  __shared__ unsigned short Bs[128 * BT];
  const int tid = threadIdx.x;
  const int bm = blockIdx.x, bn = blockIdx.y;
  const int w = tid >> 6, l = tid & 63;
  const int wr = (w >> 1) * 64, wc = (w & 1) * 64;

  f4v acc[4][4];
#pragma unroll
  for (int a = 0; a < 4; ++a)
#pragma unroll
    for (int b = 0; b < 4; ++b) {
      acc[a][b][0] = 0.f; acc[a][b][1] = 0.f; acc[a][b][2] = 0.f; acc[a][b][3] = 0.f;
    }

  const long arow0 = (long)bm * 128;
  const int brow0 = bn * 128;

  for (int kb = 0; kb < 256; kb += 32) {
#pragma unroll
    for (int cc = 0; cc < 2; ++cc) {
      int c = tid + cc * 256;
      int row = c >> 2, part = c & 3;
      uint4 av = *(const uint4*)(X + (arow0 + row) * 256 + kb + part * 8);
      *(uint4*)(&As[row * BT + part * 8]) = av;
      uint4 bv = *(const uint4*)(W + (long)(brow0 + row) * 256 + kb + part * 8);
      *(uint4*)(&Bs[row * BT + part * 8]) = bv;
    }
    __syncthreads();

    const int lr = l & 15, kg = (l >> 4) * 8;
    s8v af[4], bf[4];
#pragma unroll
    for (int mi = 0; mi < 4; ++mi) af[mi] = *(const s8v*)(&As[(wr + mi * 16 + lr) * BT + kg]);
#pragma unroll
    for (int ni = 0; ni < 4; ++ni) bf[ni] = *(const s8v*)(&Bs[(wc + ni * 16 + lr) * BT + kg]);
#pragma unroll
    for (int mi = 0; mi < 4; ++mi)
#pragma unroll
      for (int ni = 0; ni < 4; ++ni)
        acc[mi][ni] = __builtin_amdgcn_mfma_f32_16x16x32_bf16(af[mi], bf[ni], acc[mi][ni], 0, 0, 0);
    __syncthreads();
  }

  const int lr = l & 15, rg = (l >> 4) * 4;
#pragma unroll
  for (int mi = 0; mi < 4; ++mi)
#pragma unroll
    for (int ni = 0; ni < 4; ++ni) {
      int gcol = bn * 128 + wc + ni * 16 + lr;
      float bv = bias[gcol];
#pragma unroll
      for (int r = 0; r < 4; ++r) {
        long grow = arow0 + wr + mi * 16 + rg + r;
        XG[grow * 768 + gcol] = __float2half(acc[mi][ni][r] + bv);
      }
    }
}

// ---------------- phase 2: recurrence ----------------

__device__ __forceinline__ float fdot2f(h2v a, h2v b, float c) {
#if __has_builtin(__builtin_amdgcn_fdot2)
  return __builtin_amdgcn_fdot2(a, b, c, false);
#else
  return c + (float)a.x * (float)b.x + (float)a.y * (float)b.y;
#endif
}

__device__ __forceinline__ float rcp_fast(float x) {
#if __has_builtin(__builtin_amdgcn_rcpf)
  return __builtin_amdgcn_rcpf(x);
#else
  return 1.f / x;
#endif
}

// butterfly sum within each quad of lanes (pure-VALU DPP; all 4 lanes get total)
__device__ __forceinline__ float quad_red(float v) {
  int s1 = __builtin_amdgcn_update_dpp(0, __builtin_bit_cast(int, v),
                                       0xB1 /*quad_perm [1,0,3,2]*/, 0xF, 0xF, true);
  float v1 = v + __builtin_bit_cast(float, s1);
  int s2 = __builtin_amdgcn_update_dpp(0, __builtin_bit_cast(int, v1),
                                       0x4E /*quad_perm [2,3,0,1]*/, 0xF, 0xF, true);
  return v1 + __builtin_bit_cast(float, s2);
}

__device__ __forceinline__ float sel4(int p, float a, float b, float c, float d) {
  float lo = (p & 1) ? b : a;
  float hi = (p & 1) ? d : c;
  return (p & 2) ? hi : lo;
}

#define FOR12(M) M(0) M(1) M(2) M(3) M(4) M(5) M(6) M(7) M(8) M(9) M(10) M(11)

// row m (literal 0..11): W_hh row g = 256*(m/4) + rs + 64*(m%4),
// K-slice [kq*64, kq*64+64) = 8 x uint4. Plain loads (proven-safe),
// residency enforced by PIN below.
#define LOADROW(m) \
  h8 w##m##_0, w##m##_1, w##m##_2, w##m##_3, w##m##_4, w##m##_5, w##m##_6, w##m##_7; \
  { const uint4* pr_ = (const uint4*)(Whh + (long)(256 * ((m) >> 2) + rs + 64 * ((m) & 3)) * 256 + kq * 64); \
    w##m##_0 = __builtin_bit_cast(h8, pr_[0]); \
    w##m##_1 = __builtin_bit_cast(h8, pr_[1]); \
    w##m##_2 = __builtin_bit_cast(h8, pr_[2]); \
    w##m##_3 = __builtin_bit_cast(h8, pr_[3]); \
    w##m##_4 = __builtin_bit_cast(h8, pr_[4]); \
    w##m##_5 = __builtin_bit_cast(h8, pr_[5]); \
    w##m##_6 = __builtin_bit_cast(h8, pr_[6]); \
    w##m##_7 = __builtin_bit_cast(h8, pr_[7]); }

#define PINROW(m) \
  asm volatile("" : "+v"(w##m##_0), "+v"(w##m##_1), "+v"(w##m##_2), "+v"(w##m##_3), \
                    "+v"(w##m##_4), "+v"(w##m##_5), "+v"(w##m##_6), "+v"(w##m##_7));

#define DACC(m) float acc##m = 0.f;

#define DCH(m, c) \
  acc##m = fdot2f(PAIR(w##m##_##c, 0), PAIR(hq##c, 0), acc##m); \
  acc##m = fdot2f(PAIR(w##m##_##c, 1), PAIR(hq##c, 1), acc##m); \
  acc##m = fdot2f(PAIR(w##m##_##c, 2), PAIR(hq##c, 2), acc##m); \
  acc##m = fdot2f(PAIR(w##m##_##c, 3), PAIR(hq##c, 3), acc##m);

#define ROWDOT(m) DCH(m,0) DCH(m,1) DCH(m,2) DCH(m,3) DCH(m,4) DCH(m,5) DCH(m,6) DCH(m,7)

#define DRED(m) float rr##m = quad_red(acc##m);

// 32 blocks x 256 threads (4 waves, 1/SIMD -> 512-reg budget).
// thread=(rs=tid>>2, kq=tid&3); owns K-quarter kq of 12 rows (3 gates x
// 4 output cols). After quad butterfly, lane p=kq finishes j=rs+64p.
__global__ __launch_bounds__(256)
__attribute__((amdgpu_waves_per_eu(1, 1)))
void gru_rec(
    const __half* __restrict__ Whh, const __half* __restrict__ XG,
    float* __restrict__ Y) {
  const int b = blockIdx.x;
  const int tid = threadIdx.x;
  const int kq = tid & 3;
  const int rs = tid >> 2;
  const int j = rs + 64 * kq;

  __shared__ __align__(16) __half hl[2][256];

  FOR12(LOADROW)
  FOR12(PINROW)

  hl[0][j] = __float2half(0.f);
  float h_old = 0.f;
  __syncthreads();

  const unsigned short* xp = (const unsigned short*)XG + (long)b * 2048 * 768 + j;
  float* yp = Y + (long)b * 2048 * 256 + j;

  for (int t = 0; t < 2048; ++t) {
    // issue xg loads early (consumed only at gate math, ~900cy later)
    unsigned short xu_r = xp[0];
    unsigned short xr_r = xp[256];
    unsigned short xn_r = xp[512];

    const uint4* hb = (const uint4*)(&hl[t & 1][kq * 64]);
    h8 hq0 = __builtin_bit_cast(h8, hb[0]);
    h8 hq1 = __builtin_bit_cast(h8, hb[1]);
    h8 hq2 = __builtin_bit_cast(h8, hb[2]);
    h8 hq3 = __builtin_bit_cast(h8, hb[3]);
    h8 hq4 = __builtin_bit_cast(h8, hb[4]);
    h8 hq5 = __builtin_bit_cast(h8, hb[5]);
    h8 hq6 = __builtin_bit_cast(h8, hb[6]);
    h8 hq7 = __builtin_bit_cast(h8, hb[7]);

    FOR12(DACC)
    FOR12(ROWDOT)
    FOR12(DRED)

    const float su = sel4(kq, rr0, rr1, rr2, rr3);    // update-gate dot
    const float sr = sel4(kq, rr4, rr5, rr6, rr7);    // reset-gate dot
    const float sn = sel4(kq, rr8, rr9, rr10, rr11);  // new-gate dot

    const float xu = __half2float(__builtin_bit_cast(__half, xu_r));
    const float xr = __half2float(__builtin_bit_cast(__half, xr_r));
    const float xn = __half2float(__builtin_bit_cast(__half, xn_r));

    float z = rcp_fast(1.f + __expf(-(xu + su)));
    float r = rcp_fast(1.f + __expf(-(xr + sr)));
    float pre = xn + r * sn;
    float e = __expf(2.f * pre);
    float n = 1.f - 2.f * rcp_fast(1.f + e);
    float hnew = z * h_old + (1.f - z) * n;

    *yp = hnew;
    hl[(t & 1) ^ 1][j] = __float2half(hnew);
    h_old = hnew;
    xp += 768;
    yp += 256;
    __syncthreads();
  }
}

// ---------------- launch ----------------

extern "C" void kernel_launch(void* const* d_in, const int* in_sizes, int n_in,
                              void* d_out, int out_size, void* d_ws, size_t ws_size,
                              hipStream_t stream) {
  const float* x   = (const float*)d_in[0];  // [32,2048,256]
  const float* Wih = (const float*)d_in[1];  // [768,256]
  const float* bih = (const float*)d_in[2];  // [768]
  const float* Whh = (const float*)d_in[3];  // [768,256]
  float* Y = (float*)d_out;                  // [32,2048,256]

  char* ws = (char*)d_ws;
  unsigned short* x16   = (unsigned short*)ws;
  unsigned short* wih16 = (unsigned short*)(ws + 33554432);
  __half*         whh16 = (__half*)(ws + 33554432 + 393216);
  __half*         xg16  = (__half*)(ws + 33554432 + 2 * 393216);

  cvt_bf16_k<<<2048, 256, 0, stream>>>(x, x16, 16777216 / 8);
  cvt_bf16_k<<<96, 256, 0, stream>>>(Wih, wih16, 196608 / 8);
  cvt_f16_k<<<96, 256, 0, stream>>>(Whh, whh16, 196608 / 8);

  dim3 g(512, 6);
  gemm_xg<<<g, 256, 0, stream>>>(x16, wih16, bih, xg16);

  gru_rec<<<32, 256, 0, stream>>>(whh16, xg16, Y);
}

// Round 12
// 3304.676 us; speedup vs baseline: 1.4820x; 1.2758x over previous
//
#include <hip/hip_runtime.h>
#include <hip/hip_bf16.h>
#include <hip/hip_fp16.h>

// ---------------------------------------------------------------------------
// GRU forward, MI355X.
//   B=32, L=2048, D=256, H=256, 3H=768.
//   Phase 0: convert x,W_ih -> bf16 ; W_hh -> f16
//   Phase 1: xg = x @ W_ih^T + b_ih  via MFMA bf16 16x16x32, 128x128 tiles
//   Phase 2: persistent recurrence, 1 WG per batch (32 WGs), MFMA-based.
//     ROUND-12: dot2 is dead — v_dot2 needs VGPR operands and arch VGPRs
//     cap at 256/wave, but weights need 384 regs -> RA always scratch-spills
//     (R1-R11). MFMA reads AGPRs NATIVELY, the only path to all 512 regs.
//     Trick: set all 16 B-columns = h, so D[row][col] = dot(W_row,h) for
//     every col -> every lane holds valid dots, extraction is lane-local.
//     Wave w owns cols [64w,64w+64) x 3 gates = 12 N-tiles x 8 K-tiles =
//     96 MFMA/step (466 cy). 96 A-frags (384 regs, pinned) overflow into
//     AGPRs where MFMA consumes them free. 8 conflict-free broadcast
//     ds_read_b128 build B. One barrier/step.
// ---------------------------------------------------------------------------

typedef _Float16 f16x8 __attribute__((ext_vector_type(8)));
typedef __attribute__((ext_vector_type(8))) short s8v;
typedef __attribute__((ext_vector_type(4))) float f4v;

// ---------------- converts ----------------

__device__ __forceinline__ unsigned short f2bf_rne(unsigned u) {
  return (unsigned short)((u + 0x7FFFu + ((u >> 16) & 1u)) >> 16);
}

__global__ void cvt_bf16_k(const float* __restrict__ s, unsigned short* __restrict__ d, int n8) {
  int i = blockIdx.x * blockDim.x + threadIdx.x;
  int st = gridDim.x * blockDim.x;
  const uint4* sp = (const uint4*)s;
  for (; i < n8; i += st) {
    uint4 a = sp[2 * i], b = sp[2 * i + 1];
    union { unsigned short us[8]; uint4 u; } o;
    o.us[0] = f2bf_rne(a.x); o.us[1] = f2bf_rne(a.y);
    o.us[2] = f2bf_rne(a.z); o.us[3] = f2bf_rne(a.w);
    o.us[4] = f2bf_rne(b.x); o.us[5] = f2bf_rne(b.y);
    o.us[6] = f2bf_rne(b.z); o.us[7] = f2bf_rne(b.w);
    ((uint4*)d)[i] = o.u;
  }
}

__global__ void cvt_f16_k(const float* __restrict__ s, __half* __restrict__ d, int n8) {
  int i = blockIdx.x * blockDim.x + threadIdx.x;
  int st = gridDim.x * blockDim.x;
  const float4* sp = (const float4*)s;
  for (; i < n8; i += st) {
    float4 a = sp[2 * i], b = sp[2 * i + 1];
    union { uint4 u; __half2 h[4]; } o;
    o.h[0] = __floats2half2_rn(a.x, a.y);
    o.h[1] = __floats2half2_rn(a.z, a.w);
    o.h[2] = __floats2half2_rn(b.x, b.y);
    o.h[3] = __floats2half2_rn(b.z, b.w);
    ((uint4*)d)[i] = o.u;
  }
}

// ---------------- phase 1: xg GEMM (bf16 MFMA) ----------------
#define BT 48

__global__ __launch_bounds__(256) void gemm_xg(
    const unsigned short* __restrict__ X, const unsigned short* __restrict__ W,
    const float* __restrict__ bias, __half* __restrict__ XG) {
  __shared__ unsigned short As[128 * BT];
  __shared__ unsigned short Bs[128 * BT];
  const int tid = threadIdx.x;
  const int bm = blockIdx.x, bn = blockIdx.y;
  const int w = tid >> 6, l = tid & 63;
  const int wr = (w >> 1) * 64, wc = (w & 1) * 64;

  f4v acc[4][4];
#pragma unroll
  for (int a = 0; a < 4; ++a)
#pragma unroll
    for (int b = 0; b < 4; ++b) {
      acc[a][b][0] = 0.f; acc[a][b][1] = 0.f; acc[a][b][2] = 0.f; acc[a][b][3] = 0.f;
    }

  const long arow0 = (long)bm * 128;
  const int brow0 = bn * 128;

  for (int kb = 0; kb < 256; kb += 32) {
#pragma unroll
    for (int cc = 0; cc < 2; ++cc) {
      int c = tid + cc * 256;
      int row = c >> 2, part = c & 3;
      uint4 av = *(const uint4*)(X + (arow0 + row) * 256 + kb + part * 8);
      *(uint4*)(&As[row * BT + part * 8]) = av;
      uint4 bv = *(const uint4*)(W + (long)(brow0 + row) * 256 + kb + part * 8);
      *(uint4*)(&Bs[row * BT + part * 8]) = bv;
    }
    __syncthreads();

    const int lr = l & 15, kg = (l >> 4) * 8;
    s8v af[4], bf[4];
#pragma unroll
    for (int mi = 0; mi < 4; ++mi) af[mi] = *(const s8v*)(&As[(wr + mi * 16 + lr) * BT + kg]);
#pragma unroll
    for (int ni = 0; ni < 4; ++ni) bf[ni] = *(const s8v*)(&Bs[(wc + ni * 16 + lr) * BT + kg]);
#pragma unroll
    for (int mi = 0; mi < 4; ++mi)
#pragma unroll
      for (int ni = 0; ni < 4; ++ni)
        acc[mi][ni] = __builtin_amdgcn_mfma_f32_16x16x32_bf16(af[mi], bf[ni], acc[mi][ni], 0, 0, 0);
    __syncthreads();
  }

  const int lr = l & 15, rg = (l >> 4) * 4;
#pragma unroll
  for (int mi = 0; mi < 4; ++mi)
#pragma unroll
    for (int ni = 0; ni < 4; ++ni) {
      int gcol = bn * 128 + wc + ni * 16 + lr;
      float bv = bias[gcol];
#pragma unroll
      for (int r = 0; r < 4; ++r) {
        long grow = arow0 + wr + mi * 16 + rg + r;
        XG[grow * 768 + gcol] = __float2half(acc[mi][ni][r] + bv);
      }
    }
}

// ---------------- phase 2: recurrence (MFMA) ----------------

__device__ __forceinline__ float rcp_fast(float x) {
#if __has_builtin(__builtin_amdgcn_rcpf)
  return __builtin_amdgcn_rcpf(x);
#else
  return 1.f / x;
#endif
}

// per-thread scalar select of one f4v among four by p in 0..3
__device__ __forceinline__ f4v self4(int p, f4v a, f4v b, f4v c, f4v d) {
  f4v lo = (p & 1) ? b : a;
  f4v hi = (p & 1) ? d : c;
  return (p & 2) ? hi : lo;
}

// A-fragment (G=gate 0..2, Q=col-subtile 0..3, K=k-tile 0..7):
// lane l holds W_hh[row = G*256 + wv*64 + Q*16 + (l&15)][k = K*32 + (l>>4)*8 + j]
// -> one 16B load; PIN makes it a non-sinkable asm result (AV-class ok: only
// consumer is MFMA, which reads AGPRs natively).
#define LDFRAG(G, Q, K) f16x8 a_##G##_##Q##_##K; \
  { uint4 v_ = *(const uint4*)(Wb + (long)((G) * 256 + wv * 64 + (Q) * 16 + lm) * 512 + (K) * 64 + hoff); \
    a_##G##_##Q##_##K = __builtin_bit_cast(f16x8, v_); \
    asm volatile("" : "+v"(a_##G##_##Q##_##K)); }

#define REP_K8(M, G, Q) M(G,Q,0) M(G,Q,1) M(G,Q,2) M(G,Q,3) M(G,Q,4) M(G,Q,5) M(G,Q,6) M(G,Q,7)
#define REP_GQK(M) \
  REP_K8(M,0,0) REP_K8(M,0,1) REP_K8(M,0,2) REP_K8(M,0,3) \
  REP_K8(M,1,0) REP_K8(M,1,1) REP_K8(M,1,2) REP_K8(M,1,3) \
  REP_K8(M,2,0) REP_K8(M,2,1) REP_K8(M,2,2) REP_K8(M,2,3)

#define LDB(K) f16x8 bk##K = __builtin_bit_cast(f16x8, *(const uint4*)(hb + (K) * 64));

#define MF1(G, Q, K) acc_##G##_##Q = \
  __builtin_amdgcn_mfma_f32_16x16x32_f16(a_##G##_##Q##_##K, bk##K, acc_##G##_##Q, 0, 0, 0);
#define MFK(K) MF1(0,0,K) MF1(0,1,K) MF1(0,2,K) MF1(0,3,K) \
               MF1(1,0,K) MF1(1,1,K) MF1(1,2,K) MF1(1,3,K) \
               MF1(2,0,K) MF1(2,1,K) MF1(2,2,K) MF1(2,3,K)

// gate math for one of the lane's 4 outputs (literal R, xg component XC)
#define GATE(R, XC) { \
  float xu_ = __half2float(__builtin_bit_cast(__half, xu4.XC)); \
  float xr_ = __half2float(__builtin_bit_cast(__half, xr4.XC)); \
  float xn_ = __half2float(__builtin_bit_cast(__half, xn4.XC)); \
  float z_ = rcp_fast(1.f + __expf(-(xu_ + du[R]))); \
  float r_ = rcp_fast(1.f + __expf(-(xr_ + dr[R]))); \
  float pre_ = xn_ + r_ * dn[R]; \
  float e_ = __expf(2.f * pre_); \
  float n_ = 1.f - 2.f * rcp_fast(1.f + e_); \
  hn##R = z_ * hp##R + (1.f - z_) * n_; }

// 32 blocks x 256 threads (4 waves, 1/SIMD -> 512-reg budget).
// Wave wv owns output cols [64wv, 64wv+64) for all 3 gates.
// B cols all = h -> lane l holds dots for rows (l>>4)*4+r of each tile;
// lane handles the 4 outputs j = wv*64 + (l&3)*16 + (l>>4)*4 + r;
// lanes with (l&12)==0 are the writers (exactly cover the 64 cols).
__global__ __launch_bounds__(256)
__attribute__((amdgpu_waves_per_eu(1, 1)))
void gru_rec(
    const __half* __restrict__ Whh, const __half* __restrict__ XG,
    float* __restrict__ Y) {
  const int b = blockIdx.x;
  const int tid = threadIdx.x;
  const int wv = tid >> 6;
  const int l = tid & 63;
  const int lm = l & 15;
  const int hoff = (l >> 4) * 16;           // byte offset of this lane-group's k-slice
  const int q = l & 3;
  const int jb = wv * 64 + q * 16 + (l >> 4) * 4;

  __shared__ __align__(16) __half hl[2][256];

  const char* Wb = (const char*)Whh;
  REP_GQK(LDFRAG)   // 96 fragments = 384 regs, pinned

  if (tid < 32) {
    uint4 z4; z4.x = 0; z4.y = 0; z4.z = 0; z4.w = 0;
    ((uint4*)&hl[0][0])[tid] = z4;
  }
  float hp0 = 0.f, hp1 = 0.f, hp2 = 0.f, hp3 = 0.f;
  __syncthreads();

  const unsigned short* xgp = (const unsigned short*)XG + (long)b * 2048 * 768 + jb;
  float* yp = Y + (long)b * 2048 * 256 + jb;

  for (int t = 0; t < 2048; ++t) {
    // xg for this lane's 4 outputs (consumed ~500cy later, after MFMAs)
    ushort4 xu4 = *(const ushort4*)(xgp);
    ushort4 xr4 = *(const ushort4*)(xgp + 256);
    ushort4 xn4 = *(const ushort4*)(xgp + 512);

    // B-fragments: lane group (l>>4) broadcasts h[K*32 + (l>>4)*8 ..+8)
    // (4 distinct addrs/instr on distinct banks -> conflict-free)
    const char* hb = (const char*)&hl[t & 1][0] + hoff;
    LDB(0) LDB(1) LDB(2) LDB(3) LDB(4) LDB(5) LDB(6) LDB(7)

    f4v zz; zz[0] = 0.f; zz[1] = 0.f; zz[2] = 0.f; zz[3] = 0.f;
    f4v acc_0_0 = zz, acc_0_1 = zz, acc_0_2 = zz, acc_0_3 = zz;
    f4v acc_1_0 = zz, acc_1_1 = zz, acc_1_2 = zz, acc_1_3 = zz;
    f4v acc_2_0 = zz, acc_2_1 = zz, acc_2_2 = zz, acc_2_3 = zz;

    // 96 MFMA, k-outer for 12-way ILP across acc chains
    MFK(0) MFK(1) MFK(2) MFK(3) MFK(4) MFK(5) MFK(6) MFK(7)

    // this lane finishes col-subtile q = l&3: select its accs
    f4v du = self4(q, acc_0_0, acc_0_1, acc_0_2, acc_0_3);
    f4v dr = self4(q, acc_1_0, acc_1_1, acc_1_2, acc_1_3);
    f4v dn = self4(q, acc_2_0, acc_2_1, acc_2_2, acc_2_3);

    float hn0, hn1, hn2, hn3;
    GATE(0, x) GATE(1, y) GATE(2, z) GATE(3, w)

    if ((l & 12) == 0) {   // 16 writer lanes cover the wave's 64 cols
      f4v res; res[0] = hn0; res[1] = hn1; res[2] = hn2; res[3] = hn3;
      *(f4v*)yp = res;
      unsigned lo = (unsigned)__half_as_ushort(__float2half(hn0)) |
                    ((unsigned)__half_as_ushort(__float2half(hn1)) << 16);
      unsigned hi = (unsigned)__half_as_ushort(__float2half(hn2)) |
                    ((unsigned)__half_as_ushort(__float2half(hn3)) << 16);
      uint2 hw; hw.x = lo; hw.y = hi;
      *(uint2*)(&hl[(t & 1) ^ 1][jb]) = hw;
    }
    hp0 = hn0; hp1 = hn1; hp2 = hn2; hp3 = hn3;
    xgp += 768;
    yp += 256;
    __syncthreads();
  }
}

// ---------------- launch ----------------

extern "C" void kernel_launch(void* const* d_in, const int* in_sizes, int n_in,
                              void* d_out, int out_size, void* d_ws, size_t ws_size,
                              hipStream_t stream) {
  const float* x   = (const float*)d_in[0];  // [32,2048,256]
  const float* Wih = (const float*)d_in[1];  // [768,256]
  const float* bih = (const float*)d_in[2];  // [768]
  const float* Whh = (const float*)d_in[3];  // [768,256]
  float* Y = (float*)d_out;                  // [32,2048,256]

  char* ws = (char*)d_ws;
  unsigned short* x16   = (unsigned short*)ws;
  unsigned short* wih16 = (unsigned short*)(ws + 33554432);
  __half*         whh16 = (__half*)(ws + 33554432 + 393216);
  __half*         xg16  = (__half*)(ws + 33554432 + 2 * 393216);

  cvt_bf16_k<<<2048, 256, 0, stream>>>(x, x16, 16777216 / 8);
  cvt_bf16_k<<<96, 256, 0, stream>>>(Wih, wih16, 196608 / 8);
  cvt_f16_k<<<96, 256, 0, stream>>>(Whh, whh16, 196608 / 8);

  dim3 g(512, 6);
  gemm_xg<<<g, 256, 0, stream>>>(x16, wih16, bih, xg16);

  gru_rec<<<32, 256, 0, stream>>>(whh16, xg16, Y);
}